// Round 1
// baseline (1185.912 us; speedup 1.0000x reference)
//
#include <hip/hip_runtime.h>

// ---------- types ----------
typedef __attribute__((ext_vector_type(8))) short bf16x8;
typedef __attribute__((ext_vector_type(4))) float f32x4;

static __device__ __forceinline__ unsigned short f2bf(float x) {
    unsigned int u = __float_as_uint(x);
    u += 0x7fffu + ((u >> 16) & 1u);   // RTNE, finite inputs
    return (unsigned short)(u >> 16);
}

// ---------- K0: transpose fp32 [K][N] -> bf16 [N][K] ----------
__global__ void transpose_f32_bf16(const float* __restrict__ src,
                                   unsigned short* __restrict__ dst,
                                   int K, int N) {
    int idx = blockIdx.x * blockDim.x + threadIdx.x;
    if (idx >= K * N) return;
    int k = idx / N;
    int n = idx - k * N;                 // consecutive idx -> consecutive n: coalesced read
    dst[(size_t)n * K + k] = f2bf(src[idx]);
}

// ---------- GEMM: C[M,N] = A[M,K] @ Bt[N,K]^T + bias, bf16 MFMA ----------
// GATHER: A row r comes from emb[tokens[r]] (fp32, converted on the fly)
// else:   A is bf16 row-major [M,K]
template<bool GATHER>
__global__ __launch_bounds__(256, 4) void gemm_mfma(
    const void* __restrict__ Aptr, const int* __restrict__ tokens,
    const unsigned short* __restrict__ Bt, const float* __restrict__ bias,
    float* __restrict__ C, int M, int N, int K)
{
    const int bn0 = blockIdx.x * 64;
    const int m0  = blockIdx.y * 64;
    const int tid = threadIdx.x;

    __shared__ unsigned short As[64 * 40];   // 64 m-rows x 32 k, pad 40
    __shared__ unsigned short Bs[64 * 40];   // 64 n-rows x 32 k
    __shared__ int tok[64];

    if (GATHER) {
        if (tid < 64) tok[tid] = tokens[m0 + tid];
        __syncthreads();
    }

    const int r  = tid >> 2;          // staging row 0..63
    const int c0 = (tid & 3) * 8;     // staging k-offset 0,8,16,24
    const int w  = tid >> 6;          // wave 0..3
    const int L  = tid & 63;
    const int ml = L & 15;
    const int q  = L >> 4;
    const int kq = q * 8;

    f32x4 acc[4] = {};

    for (int k0 = 0; k0 < K; k0 += 32) {
        // ---- stage A tile ----
        unsigned short tmp[8];
        if (GATHER) {
            const float* src = (const float*)Aptr + (size_t)tok[r] * K + k0 + c0;
            float4 f0 = *(const float4*)(src);
            float4 f1 = *(const float4*)(src + 4);
            tmp[0]=f2bf(f0.x); tmp[1]=f2bf(f0.y); tmp[2]=f2bf(f0.z); tmp[3]=f2bf(f0.w);
            tmp[4]=f2bf(f1.x); tmp[5]=f2bf(f1.y); tmp[6]=f2bf(f1.z); tmp[7]=f2bf(f1.w);
        } else {
            const unsigned short* src = (const unsigned short*)Aptr + (size_t)(m0 + r) * K + k0 + c0;
            *(uint4*)tmp = *(const uint4*)src;
        }
        *(uint4*)&As[r * 40 + c0] = *(const uint4*)tmp;
        // ---- stage B tile (Bt is [N][K] bf16) ----
        *(uint4*)&Bs[r * 40 + c0] = *(const uint4*)(Bt + (size_t)(bn0 + r) * K + k0 + c0);
        __syncthreads();

        bf16x8 av = *(const bf16x8*)&As[(16 * w + ml) * 40 + kq];
#pragma unroll
        for (int ns = 0; ns < 4; ++ns) {
            bf16x8 bv = *(const bf16x8*)&Bs[(ns * 16 + ml) * 40 + kq];
            acc[ns] = __builtin_amdgcn_mfma_f32_16x16x32_bf16(av, bv, acc[ns], 0, 0, 0);
        }
        __syncthreads();
    }

#pragma unroll
    for (int ns = 0; ns < 4; ++ns) {
        int gn = bn0 + ns * 16 + ml;
        float bv = bias[gn];
#pragma unroll
        for (int rr = 0; rr < 4; ++rr) {
            int gm = m0 + 16 * w + q * 4 + rr;
            C[(size_t)gm * N + gn] = acc[ns][rr] + bv;
        }
    }
}

// ---------- scan: h_t = tanh(xw_t + h_{t-1} @ U), one WG per batch row ----------
// 512 threads: j = tid&255 (output col), p = tid>>8 (K-half). U column slice in VGPRs.
__global__ __launch_bounds__(512, 2) void rnn_scan(
    const float* __restrict__ xw,      // [64][512][256]
    const float* __restrict__ U,       // [256][256]
    unsigned short* __restrict__ out_seq, // bf16 [64][512][256] (or null)
    float* __restrict__ out_last,         // f32 [64][256] (or null)
    int seq_out)
{
    const int b   = blockIdx.x;
    const int tid = threadIdx.x;
    const int j   = tid & 255;
    const int p   = tid >> 8;

    float Ureg[128];
#pragma unroll
    for (int i = 0; i < 128; ++i) Ureg[i] = U[(size_t)(p * 128 + i) * 256 + j];

    __shared__ float hsh[256];
    __shared__ float part[256];
    if (p == 0) hsh[j] = 0.f;

    const float* xb = xw + (size_t)b * 512 * 256;
    float xv = (p == 0) ? xb[j] : 0.f;

    for (int t = 0; t < 512; ++t) {
        __syncthreads();                       // h ready for this step
        float xnext = 0.f;
        if (p == 0 && t + 1 < 512) xnext = xb[(size_t)(t + 1) * 256 + j];  // prefetch

        const float4* h4 = (const float4*)&hsh[p * 128];
        float a0 = 0.f, a1 = 0.f, a2 = 0.f, a3 = 0.f;
#pragma unroll
        for (int i = 0; i < 32; ++i) {
            float4 hv = h4[i];                 // wave-uniform address -> LDS broadcast
            a0 = fmaf(hv.x, Ureg[4 * i + 0], a0);
            a1 = fmaf(hv.y, Ureg[4 * i + 1], a1);
            a2 = fmaf(hv.z, Ureg[4 * i + 2], a2);
            a3 = fmaf(hv.w, Ureg[4 * i + 3], a3);
        }
        float acc = (a0 + a1) + (a2 + a3);
        if (p) part[j] = acc;
        __syncthreads();                       // partials visible
        if (p == 0) {
            float pre = xv + acc + part[j];
            float e  = __expf(2.f * pre);      // tanh(x) = 1 - 2/(e^{2x}+1); inf-safe
            float hn = 1.f - 2.f / (e + 1.f);
            hsh[j] = hn;
            if (seq_out)       out_seq[(size_t)b * 512 * 256 + (size_t)t * 256 + j] = f2bf(hn);
            else if (t == 511) out_last[b * 256 + j] = hn;
        }
        xv = xnext;
    }
}

// ---------- head: softmax(h2 @ Wd + bd) ----------
__global__ void head_kernel(const float* __restrict__ h2, const float* __restrict__ Wd,
                            const float* __restrict__ bd, float* __restrict__ out)
{
    int tid = threadIdx.x;         // 128 threads: b = tid>>1, c = tid&1
    int b = tid >> 1, c = tid & 1;
    float s = bd[c];
    for (int jj = 0; jj < 256; ++jj) s = fmaf(h2[b * 256 + jj], Wd[jj * 2 + c], s);
    __shared__ float lg[128];
    lg[tid] = s;
    __syncthreads();
    float o0 = lg[b * 2 + 0], o1 = lg[b * 2 + 1];
    float m = fmaxf(o0, o1);
    float z = __expf(o0 - m) + __expf(o1 - m);
    out[tid] = __expf(s - m) / z;
}

// ---------- launch ----------
extern "C" void kernel_launch(void* const* d_in, const int* in_sizes, int n_in,
                              void* d_out, int out_size, void* d_ws, size_t ws_size,
                              hipStream_t stream) {
    const int*   tokens = (const int*)d_in[0];
    const float* emb    = (const float*)d_in[1];
    const float* W1     = (const float*)d_in[2];
    const float* U1     = (const float*)d_in[3];
    const float* b1     = (const float*)d_in[4];
    const float* W2     = (const float*)d_in[5];
    const float* U2     = (const float*)d_in[6];
    const float* b2     = (const float*)d_in[7];
    const float* Wd     = (const float*)d_in[8];
    const float* bd     = (const float*)d_in[9];
    float* out = (float*)d_out;

    char* ws = (char*)d_ws;
    // layout: xw f32 (32 MB, reused for xw1 then xw2) | h1 bf16 (16 MB) | W1t | W2t | h2
    float*          xw  = (float*)ws;
    unsigned short* h1  = (unsigned short*)(ws + 33554432);
    unsigned short* W1t = (unsigned short*)(ws + 33554432 + 16777216);
    unsigned short* W2t = W1t + 512 * 256;
    float*          h2  = (float*)(W2t + 256 * 256);

    const int M = 64 * 512;   // 32768

    // K0: weight transposes to bf16 [N][K]
    transpose_f32_bf16<<<(512 * 256 + 255) / 256, 256, 0, stream>>>(W1, W1t, 512, 256);
    transpose_f32_bf16<<<(256 * 256 + 255) / 256, 256, 0, stream>>>(W2, W2t, 256, 256);

    // K1: xw1 = emb[tokens] @ W1 + b1   (gather fused)
    gemm_mfma<true><<<dim3(256 / 64, M / 64), 256, 0, stream>>>(
        emb, tokens, W1t, b1, xw, M, 256, 512);

    // K2: layer-1 scan -> h1 (bf16, full sequence)
    rnn_scan<<<64, 512, 0, stream>>>(xw, U1, h1, nullptr, 1);

    // K3: xw2 = h1 @ W2 + b2
    gemm_mfma<false><<<dim3(256 / 64, M / 64), 256, 0, stream>>>(
        h1, nullptr, W2t, b2, xw, M, 256, 256);

    // K4: layer-2 scan -> h2 (last state, f32)
    rnn_scan<<<64, 512, 0, stream>>>(xw, U2, nullptr, h2, 0);

    // K5: softmax(h2 @ Wd + bd)
    head_kernel<<<1, 128, 0, stream>>>(h2, Wd, bd, out);
}

// Round 2
// 781.744 us; speedup vs baseline: 1.5170x; 1.5170x over previous
//
#include <hip/hip_runtime.h>

// ---------- types ----------
typedef __attribute__((ext_vector_type(8))) short bf16x8;
typedef __attribute__((ext_vector_type(4))) float f32x4;

static __device__ __forceinline__ unsigned short f2bf(float x) {
    unsigned int u = __float_as_uint(x);
    u += 0x7fffu + ((u >> 16) & 1u);   // RTNE, finite inputs
    return (unsigned short)(u >> 16);
}

// ---------- K0: four fp32->bf16 transposes in one launch ----------
// dst[n*K+k] = bf16(src[k*N+n]), N=256 for all four. which: 0=W1(K=512),1=W2,2=U1,3=U2
__global__ void transpose4(const float* __restrict__ s0, const float* __restrict__ s1,
                           const float* __restrict__ s2, const float* __restrict__ s3,
                           unsigned short* __restrict__ d0, unsigned short* __restrict__ d1,
                           unsigned short* __restrict__ d2, unsigned short* __restrict__ d3) {
    int which = blockIdx.y;
    const float* src = which == 0 ? s0 : which == 1 ? s1 : which == 2 ? s2 : s3;
    unsigned short* dst = which == 0 ? d0 : which == 1 ? d1 : which == 2 ? d2 : d3;
    int K = (which == 0) ? 512 : 256;
    int idx = blockIdx.x * 256 + threadIdx.x;
    if (idx >= K * 256) return;
    int k = idx >> 8;          // N = 256
    int n = idx & 255;
    dst[n * K + k] = f2bf(src[idx]);
}

// ---------- GEMM: C[M,N] = A[M,K] @ Bt[N,K]^T + bias, bf16 MFMA ----------
template<bool GATHER>
__global__ __launch_bounds__(256, 4) void gemm_mfma(
    const void* __restrict__ Aptr, const int* __restrict__ tokens,
    const unsigned short* __restrict__ Bt, const float* __restrict__ bias,
    float* __restrict__ C, int M, int N, int K)
{
    const int bn0 = blockIdx.x * 64;
    const int m0  = blockIdx.y * 64;
    const int tid = threadIdx.x;

    __shared__ unsigned short As[64 * 40];
    __shared__ unsigned short Bs[64 * 40];
    __shared__ int tok[64];

    if (GATHER) {
        if (tid < 64) tok[tid] = tokens[m0 + tid];
        __syncthreads();
    }

    const int r  = tid >> 2;
    const int c0 = (tid & 3) * 8;
    const int w  = tid >> 6;
    const int L  = tid & 63;
    const int ml = L & 15;
    const int q  = L >> 4;
    const int kq = q * 8;

    f32x4 acc[4] = {};

    for (int k0 = 0; k0 < K; k0 += 32) {
        unsigned short tmp[8];
        if (GATHER) {
            const float* src = (const float*)Aptr + (size_t)tok[r] * K + k0 + c0;
            float4 f0 = *(const float4*)(src);
            float4 f1 = *(const float4*)(src + 4);
            tmp[0]=f2bf(f0.x); tmp[1]=f2bf(f0.y); tmp[2]=f2bf(f0.z); tmp[3]=f2bf(f0.w);
            tmp[4]=f2bf(f1.x); tmp[5]=f2bf(f1.y); tmp[6]=f2bf(f1.z); tmp[7]=f2bf(f1.w);
        } else {
            const unsigned short* src = (const unsigned short*)Aptr + (size_t)(m0 + r) * K + k0 + c0;
            *(uint4*)tmp = *(const uint4*)src;
        }
        *(uint4*)&As[r * 40 + c0] = *(const uint4*)tmp;
        *(uint4*)&Bs[r * 40 + c0] = *(const uint4*)(Bt + (size_t)(bn0 + r) * K + k0 + c0);
        __syncthreads();

        bf16x8 av = *(const bf16x8*)&As[(16 * w + ml) * 40 + kq];
#pragma unroll
        for (int ns = 0; ns < 4; ++ns) {
            bf16x8 bv = *(const bf16x8*)&Bs[(ns * 16 + ml) * 40 + kq];
            acc[ns] = __builtin_amdgcn_mfma_f32_16x16x32_bf16(av, bv, acc[ns], 0, 0, 0);
        }
        __syncthreads();
    }

#pragma unroll
    for (int ns = 0; ns < 4; ++ns) {
        int gn = bn0 + ns * 16 + ml;
        float bv = bias[gn];
#pragma unroll
        for (int rr = 0; rr < 4; ++rr) {
            int gm = m0 + 16 * w + q * 4 + rr;
            C[(size_t)gm * N + gn] = acc[ns][rr] + bv;
        }
    }
}

// ---------- MFMA scan: h_t = tanh(xw_t + h_{t-1} @ U), one WG (256 thr) per batch row ----------
// A rows are replicated (every lane's A-frag = h[k-slice of its quad]) so C[r][c] = z[c] for all
// rows/regs. Wave w covers cols [w*64, w*64+64); lane L owns col w*64+L via acc[q][0].
// U held in VGPRs as B-frags, loaded from Ut[n][k] bf16 (contiguous b128 per frag).
template<bool SEQ>
__global__ __launch_bounds__(256, 1) void rnn_scan_mfma(
    const float* __restrict__ xw,           // [64][512][256] f32
    const unsigned short* __restrict__ Ut,  // [256][256] bf16, Ut[n][k] = U[k][n]
    unsigned short* __restrict__ out_seq,   // bf16 [64][512][256]  (SEQ)
    float* __restrict__ out_last)           // f32 [64][256]        (!SEQ)
{
    const int b   = blockIdx.x;
    const int tid = threadIdx.x;
    const int w   = tid >> 6;       // wave 0..3
    const int L   = tid & 63;
    const int col = w * 64 + L;     // this thread's output column
    const int q   = L >> 4;         // quad
    const int ml  = L & 15;

    __shared__ unsigned short hsh[256];

    // B-fragments: frag(i=nt-w*4, kt) -> lane needs Ut[(w*4+i)*16+ml][kt*32 + q*8 .. +7]
    bf16x8 ufrag[4][8];
#pragma unroll
    for (int i = 0; i < 4; ++i) {
        const unsigned short* up = Ut + (size_t)((w * 4 + i) * 16 + ml) * 256 + q * 8;
#pragma unroll
        for (int kt = 0; kt < 8; ++kt)
            ufrag[i][kt] = *(const bf16x8*)(up + kt * 32);
    }

    hsh[tid] = 0;   // bf16 +0.0

    const float* xb = xw + (size_t)b * 512 * 256 + col;
    float xv = xb[0];

    __syncthreads();

    for (int t = 0; t < 512; ++t) {
        // A-frags from current h (wave-uniform per quad)
        bf16x8 af[8];
#pragma unroll
        for (int kt = 0; kt < 8; ++kt)
            af[kt] = *(const bf16x8*)&hsh[kt * 32 + q * 8];

        // prefetch next step's xw (coalesced: lane L -> col w*64+L)
        float xn = 0.f;
        if (t + 1 < 512) xn = xb[(size_t)(t + 1) * 256];

        f32x4 acc[4] = {};
#pragma unroll
        for (int kt = 0; kt < 8; ++kt) {
#pragma unroll
            for (int i = 0; i < 4; ++i)
                acc[i] = __builtin_amdgcn_mfma_f32_16x16x32_bf16(af[kt], ufrag[i][kt], acc[i], 0, 0, 0);
        }

        float z = (q == 0) ? acc[0][0] : (q == 1) ? acc[1][0] : (q == 2) ? acc[2][0] : acc[3][0];
        z += xv;
        float e  = __expf(2.f * z);              // tanh(z) = 1 - 2/(e^{2z}+1); inf-safe
        float hn = 1.f - 2.f / (e + 1.f);
        unsigned short hb = f2bf(hn);

        __syncthreads();                          // all A-frag reads of h_old done
        hsh[col] = hb;
        if (SEQ) {
            out_seq[(size_t)b * 512 * 256 + (size_t)t * 256 + col] = hb;
        } else if (t == 511) {
            out_last[b * 256 + col] = hn;
        }
        xv = xn;
        __syncthreads();                          // h_new visible
    }
}

// ---------- head: softmax(h2 @ Wd + bd) ----------
__global__ void head_kernel(const float* __restrict__ h2, const float* __restrict__ Wd,
                            const float* __restrict__ bd, float* __restrict__ out)
{
    int tid = threadIdx.x;         // 128 threads: b = tid>>1, c = tid&1
    int b = tid >> 1, c = tid & 1;
    float s = bd[c];
    for (int jj = 0; jj < 256; ++jj) s = fmaf(h2[b * 256 + jj], Wd[jj * 2 + c], s);
    __shared__ float lg[128];
    lg[tid] = s;
    __syncthreads();
    float o0 = lg[b * 2 + 0], o1 = lg[b * 2 + 1];
    float m = fmaxf(o0, o1);
    float z = __expf(o0 - m) + __expf(o1 - m);
    out[tid] = __expf(s - m) / z;
}

// ---------- launch ----------
extern "C" void kernel_launch(void* const* d_in, const int* in_sizes, int n_in,
                              void* d_out, int out_size, void* d_ws, size_t ws_size,
                              hipStream_t stream) {
    const int*   tokens = (const int*)d_in[0];
    const float* emb    = (const float*)d_in[1];
    const float* W1     = (const float*)d_in[2];
    const float* U1     = (const float*)d_in[3];
    const float* b1     = (const float*)d_in[4];
    const float* W2     = (const float*)d_in[5];
    const float* U2     = (const float*)d_in[6];
    const float* b2     = (const float*)d_in[7];
    const float* Wd     = (const float*)d_in[8];
    const float* bd     = (const float*)d_in[9];
    float* out = (float*)d_out;

    char* ws = (char*)d_ws;
    float*          xw  = (float*)ws;                                  // 32 MB (xw1 then xw2)
    unsigned short* h1  = (unsigned short*)(ws + (33554432));          // 16 MB bf16
    char*           p   = ws + 33554432 + 16777216;
    unsigned short* W1t = (unsigned short*)p;            p += 512 * 256 * 2;
    unsigned short* W2t = (unsigned short*)p;            p += 256 * 256 * 2;
    unsigned short* U1t = (unsigned short*)p;            p += 256 * 256 * 2;
    unsigned short* U2t = (unsigned short*)p;            p += 256 * 256 * 2;
    float*          h2  = (float*)p;

    const int M = 64 * 512;   // 32768

    // K0: weight/recurrence transposes to bf16 [N][K]
    transpose4<<<dim3(512, 4), 256, 0, stream>>>(W1, W2, U1, U2, W1t, W2t, U1t, U2t);

    // K1: xw1 = emb[tokens] @ W1 + b1   (gather fused)
    gemm_mfma<true><<<dim3(256 / 64, M / 64), 256, 0, stream>>>(
        emb, tokens, W1t, b1, xw, M, 256, 512);

    // K2: layer-1 scan -> h1 (bf16 sequence)
    rnn_scan_mfma<true><<<64, 256, 0, stream>>>(xw, U1t, h1, nullptr);

    // K3: xw2 = h1 @ W2 + b2
    gemm_mfma<false><<<dim3(256 / 64, M / 64), 256, 0, stream>>>(
        h1, nullptr, W2t, b2, xw, M, 256, 256);

    // K4: layer-2 scan -> h2 (last state, f32)
    rnn_scan_mfma<false><<<64, 256, 0, stream>>>(xw, U2t, nullptr, h2);

    // K5: softmax(h2 @ Wd + bd)
    head_kernel<<<1, 128, 0, stream>>>(h2, Wd, bd, out);
}

// Round 3
// 704.412 us; speedup vs baseline: 1.6836x; 1.1098x over previous
//
#include <hip/hip_runtime.h>

// ---------- types ----------
typedef __attribute__((ext_vector_type(8))) short bf16x8;
typedef __attribute__((ext_vector_type(4))) float f32x4;

static __device__ __forceinline__ unsigned short f2bf(float x) {
    unsigned int u = __float_as_uint(x);
    u += 0x7fffu + ((u >> 16) & 1u);   // RTNE, finite inputs
    return (unsigned short)(u >> 16);
}

// Workgroup barrier WITHOUT vmcnt drain: LDS ordering only.
// Safe when no global-memory producer/consumer relationship crosses the barrier.
static __device__ __forceinline__ void barrier_lds_only() {
    __asm__ volatile("s_waitcnt lgkmcnt(0)\n\ts_barrier" ::: "memory");
}

// ---------- K0: four fp32->bf16 transposes in one launch ----------
__global__ void transpose4(const float* __restrict__ s0, const float* __restrict__ s1,
                           const float* __restrict__ s2, const float* __restrict__ s3,
                           unsigned short* __restrict__ d0, unsigned short* __restrict__ d1,
                           unsigned short* __restrict__ d2, unsigned short* __restrict__ d3) {
    int which = blockIdx.y;
    const float* src = which == 0 ? s0 : which == 1 ? s1 : which == 2 ? s2 : s3;
    unsigned short* dst = which == 0 ? d0 : which == 1 ? d1 : which == 2 ? d2 : d3;
    int K = (which == 0) ? 512 : 256;
    int idx = blockIdx.x * 256 + threadIdx.x;
    if (idx >= K * 256) return;
    int k = idx >> 8;          // N = 256
    int n = idx & 255;
    dst[n * K + k] = f2bf(src[idx]);
}

// ---------- GEMM: C[M,N] = A[M,K] @ Bt[N,K]^T + bias, bf16 MFMA ----------
template<bool GATHER>
__global__ __launch_bounds__(256, 4) void gemm_mfma(
    const void* __restrict__ Aptr, const int* __restrict__ tokens,
    const unsigned short* __restrict__ Bt, const float* __restrict__ bias,
    float* __restrict__ C, int M, int N, int K)
{
    const int bn0 = blockIdx.x * 64;
    const int m0  = blockIdx.y * 64;
    const int tid = threadIdx.x;

    __shared__ unsigned short As[64 * 40];
    __shared__ unsigned short Bs[64 * 40];
    __shared__ int tok[64];

    if (GATHER) {
        if (tid < 64) tok[tid] = tokens[m0 + tid];
        __syncthreads();
    }

    const int r  = tid >> 2;
    const int c0 = (tid & 3) * 8;
    const int w  = tid >> 6;
    const int L  = tid & 63;
    const int ml = L & 15;
    const int q  = L >> 4;
    const int kq = q * 8;

    f32x4 acc[4] = {};

    for (int k0 = 0; k0 < K; k0 += 32) {
        unsigned short tmp[8];
        if (GATHER) {
            const float* src = (const float*)Aptr + (size_t)tok[r] * K + k0 + c0;
            float4 f0 = *(const float4*)(src);
            float4 f1 = *(const float4*)(src + 4);
            tmp[0]=f2bf(f0.x); tmp[1]=f2bf(f0.y); tmp[2]=f2bf(f0.z); tmp[3]=f2bf(f0.w);
            tmp[4]=f2bf(f1.x); tmp[5]=f2bf(f1.y); tmp[6]=f2bf(f1.z); tmp[7]=f2bf(f1.w);
        } else {
            const unsigned short* src = (const unsigned short*)Aptr + (size_t)(m0 + r) * K + k0 + c0;
            *(uint4*)tmp = *(const uint4*)src;
        }
        *(uint4*)&As[r * 40 + c0] = *(const uint4*)tmp;
        *(uint4*)&Bs[r * 40 + c0] = *(const uint4*)(Bt + (size_t)(bn0 + r) * K + k0 + c0);
        __syncthreads();

        bf16x8 av = *(const bf16x8*)&As[(16 * w + ml) * 40 + kq];
#pragma unroll
        for (int ns = 0; ns < 4; ++ns) {
            bf16x8 bv = *(const bf16x8*)&Bs[(ns * 16 + ml) * 40 + kq];
            acc[ns] = __builtin_amdgcn_mfma_f32_16x16x32_bf16(av, bv, acc[ns], 0, 0, 0);
        }
        __syncthreads();
    }

#pragma unroll
    for (int ns = 0; ns < 4; ++ns) {
        int gn = bn0 + ns * 16 + ml;
        float bv = bias[gn];
#pragma unroll
        for (int rr = 0; rr < 4; ++rr) {
            int gm = m0 + 16 * w + q * 4 + rr;
            C[(size_t)gm * N + gn] = acc[ns][rr] + bv;
        }
    }
}

// ---------- MFMA scan: h_t = tanh(xw_t + h_{t-1} @ U), one WG (256 thr) per batch row ----------
// Double-buffered h in LDS, ONE lds-only barrier per step (no vmcnt drain),
// 4-deep register pipeline on the xw stream.
template<bool SEQ>
__global__ __launch_bounds__(256, 1) void rnn_scan_mfma(
    const float* __restrict__ xw,           // [64][512][256] f32
    const unsigned short* __restrict__ Ut,  // [256][256] bf16, Ut[n][k] = U[k][n]
    unsigned short* __restrict__ out_seq,   // bf16 [64][512][256]  (SEQ)
    float* __restrict__ out_last)           // f32 [64][256]        (!SEQ)
{
    const int b   = blockIdx.x;
    const int tid = threadIdx.x;
    const int w   = tid >> 6;       // wave 0..3
    const int L   = tid & 63;
    const int col = w * 64 + L;     // this thread's output column
    const int q   = L >> 4;         // quad
    const int ml  = L & 15;

    __shared__ unsigned short hsh[2][256];

    // B-fragments: U columns for this wave's 4 n-tiles, all 8 k-tiles
    bf16x8 ufrag[4][8];
#pragma unroll
    for (int i = 0; i < 4; ++i) {
        const unsigned short* up = Ut + (size_t)((w * 4 + i) * 16 + ml) * 256 + q * 8;
#pragma unroll
        for (int kt = 0; kt < 8; ++kt)
            ufrag[i][kt] = *(const bf16x8*)(up + kt * 32);
    }

    hsh[0][tid] = 0;   // bf16 +0.0

    const float* xb = xw + (size_t)b * 512 * 256 + col;
    unsigned short* ob = SEQ ? out_seq + (size_t)b * 512 * 256 + col : nullptr;

    // 4-deep xw prefetch pipeline
    float xq0 = xb[0 * 256];
    float xq1 = xb[1 * 256];
    float xq2 = xb[2 * 256];
    float xq3 = xb[3 * 256];

    __syncthreads();

#pragma unroll 4
    for (int t = 0; t < 512; ++t) {
        const int cur = t & 1;
        const int slot = t & 3;

        // issue next prefetch early (consumed 4 steps later)
        float xn = 0.f;
        if (t + 4 < 512) xn = xb[(size_t)(t + 4) * 256];

        // A-frags from current h (wave-uniform per quad)
        bf16x8 af[8];
#pragma unroll
        for (int kt = 0; kt < 8; ++kt)
            af[kt] = *(const bf16x8*)&hsh[cur][kt * 32 + q * 8];

        f32x4 acc[4] = {};
#pragma unroll
        for (int kt = 0; kt < 8; ++kt) {
#pragma unroll
            for (int i = 0; i < 4; ++i)
                acc[i] = __builtin_amdgcn_mfma_f32_16x16x32_bf16(af[kt], ufrag[i][kt], acc[i], 0, 0, 0);
        }

        float xv = (slot == 0) ? xq0 : (slot == 1) ? xq1 : (slot == 2) ? xq2 : xq3;
        float z = (q == 0) ? acc[0][0] : (q == 1) ? acc[1][0] : (q == 2) ? acc[2][0] : acc[3][0];
        z += xv;
        float e  = __expf(2.f * z);              // tanh(z) = 1 - 2/(e^{2z}+1); inf-safe
        float hn = 1.f - 2.f / (e + 1.f);
        unsigned short hb = f2bf(hn);

        hsh[cur ^ 1][col] = hb;                  // write next buffer
        if (SEQ) {
            ob[(size_t)t * 256] = hb;            // fire-and-forget store
        } else if (t == 511) {
            out_last[b * 256 + col] = hn;
        }

        if (slot == 0) xq0 = xn; else if (slot == 1) xq1 = xn;
        else if (slot == 2) xq2 = xn; else xq3 = xn;

        barrier_lds_only();                      // h_new visible; no vmcnt drain
    }
}

// ---------- head: softmax(h2 @ Wd + bd) ----------
__global__ void head_kernel(const float* __restrict__ h2, const float* __restrict__ Wd,
                            const float* __restrict__ bd, float* __restrict__ out)
{
    int tid = threadIdx.x;         // 128 threads: b = tid>>1, c = tid&1
    int b = tid >> 1, c = tid & 1;
    float s = bd[c];
    for (int jj = 0; jj < 256; ++jj) s = fmaf(h2[b * 256 + jj], Wd[jj * 2 + c], s);
    __shared__ float lg[128];
    lg[tid] = s;
    __syncthreads();
    float o0 = lg[b * 2 + 0], o1 = lg[b * 2 + 1];
    float m = fmaxf(o0, o1);
    float z = __expf(o0 - m) + __expf(o1 - m);
    out[tid] = __expf(s - m) / z;
}

// ---------- launch ----------
extern "C" void kernel_launch(void* const* d_in, const int* in_sizes, int n_in,
                              void* d_out, int out_size, void* d_ws, size_t ws_size,
                              hipStream_t stream) {
    const int*   tokens = (const int*)d_in[0];
    const float* emb    = (const float*)d_in[1];
    const float* W1     = (const float*)d_in[2];
    const float* U1     = (const float*)d_in[3];
    const float* b1     = (const float*)d_in[4];
    const float* W2     = (const float*)d_in[5];
    const float* U2     = (const float*)d_in[6];
    const float* b2     = (const float*)d_in[7];
    const float* Wd     = (const float*)d_in[8];
    const float* bd     = (const float*)d_in[9];
    float* out = (float*)d_out;

    char* ws = (char*)d_ws;
    float*          xw  = (float*)ws;                                  // 32 MB (xw1 then xw2)
    unsigned short* h1  = (unsigned short*)(ws + (33554432));          // 16 MB bf16
    char*           p   = ws + 33554432 + 16777216;
    unsigned short* W1t = (unsigned short*)p;            p += 512 * 256 * 2;
    unsigned short* W2t = (unsigned short*)p;            p += 256 * 256 * 2;
    unsigned short* U1t = (unsigned short*)p;            p += 256 * 256 * 2;
    unsigned short* U2t = (unsigned short*)p;            p += 256 * 256 * 2;
    float*          h2  = (float*)p;

    const int M = 64 * 512;   // 32768

    // K0: weight/recurrence transposes to bf16 [N][K]
    transpose4<<<dim3(512, 4), 256, 0, stream>>>(W1, W2, U1, U2, W1t, W2t, U1t, U2t);

    // K1: xw1 = emb[tokens] @ W1 + b1   (gather fused)
    gemm_mfma<true><<<dim3(256 / 64, M / 64), 256, 0, stream>>>(
        emb, tokens, W1t, b1, xw, M, 256, 512);

    // K2: layer-1 scan -> h1 (bf16 sequence)
    rnn_scan_mfma<true><<<64, 256, 0, stream>>>(xw, U1t, h1, nullptr);

    // K3: xw2 = h1 @ W2 + b2
    gemm_mfma<false><<<dim3(256 / 64, M / 64), 256, 0, stream>>>(
        h1, nullptr, W2t, b2, xw, M, 256, 256);

    // K4: layer-2 scan -> h2 (last state, f32)
    rnn_scan_mfma<false><<<64, 256, 0, stream>>>(xw, U2t, nullptr, h2);

    // K5: softmax(h2 @ Wd + bd)
    head_kernel<<<1, 128, 0, stream>>>(h2, Wd, bd, out);
}

// Round 4
// 660.111 us; speedup vs baseline: 1.7965x; 1.0671x over previous
//
#include <hip/hip_runtime.h>

// ---------- types ----------
typedef __attribute__((ext_vector_type(8))) short bf16x8;
typedef __attribute__((ext_vector_type(4))) float f32x4;

static __device__ __forceinline__ unsigned short f2bf(float x) {
    unsigned int u = __float_as_uint(x);
    u += 0x7fffu + ((u >> 16) & 1u);   // RTNE, finite inputs
    return (unsigned short)(u >> 16);
}

// Workgroup barrier WITHOUT vmcnt drain: LDS ordering only.
// Safe when no global-memory producer/consumer relationship crosses the barrier.
static __device__ __forceinline__ void barrier_lds_only() {
    __asm__ volatile("s_waitcnt lgkmcnt(0)\n\ts_barrier" ::: "memory");
}

// ---------- K0: four fp32->bf16 transposes in one launch ----------
__global__ void transpose4(const float* __restrict__ s0, const float* __restrict__ s1,
                           const float* __restrict__ s2, const float* __restrict__ s3,
                           unsigned short* __restrict__ d0, unsigned short* __restrict__ d1,
                           unsigned short* __restrict__ d2, unsigned short* __restrict__ d3) {
    int which = blockIdx.y;
    const float* src = which == 0 ? s0 : which == 1 ? s1 : which == 2 ? s2 : s3;
    unsigned short* dst = which == 0 ? d0 : which == 1 ? d1 : which == 2 ? d2 : d3;
    int K = (which == 0) ? 512 : 256;
    int idx = blockIdx.x * 256 + threadIdx.x;
    if (idx >= K * 256) return;
    int k = idx >> 8;          // N = 256
    int n = idx & 255;
    dst[n * K + k] = f2bf(src[idx]);
}

// ---------- GEMM: C[M,N] = A[M,K] @ Bt[N,K]^T + bias, bf16 MFMA ----------
template<bool GATHER>
__global__ __launch_bounds__(256, 4) void gemm_mfma(
    const void* __restrict__ Aptr, const int* __restrict__ tokens,
    const unsigned short* __restrict__ Bt, const float* __restrict__ bias,
    float* __restrict__ C, int M, int N, int K)
{
    const int bn0 = blockIdx.x * 64;
    const int m0  = blockIdx.y * 64;
    const int tid = threadIdx.x;

    __shared__ unsigned short As[64 * 40];
    __shared__ unsigned short Bs[64 * 40];
    __shared__ int tok[64];

    if (GATHER) {
        if (tid < 64) tok[tid] = tokens[m0 + tid];
        __syncthreads();
    }

    const int r  = tid >> 2;
    const int c0 = (tid & 3) * 8;
    const int w  = tid >> 6;
    const int L  = tid & 63;
    const int ml = L & 15;
    const int q  = L >> 4;
    const int kq = q * 8;

    f32x4 acc[4] = {};

    for (int k0 = 0; k0 < K; k0 += 32) {
        unsigned short tmp[8];
        if (GATHER) {
            const float* src = (const float*)Aptr + (size_t)tok[r] * K + k0 + c0;
            float4 f0 = *(const float4*)(src);
            float4 f1 = *(const float4*)(src + 4);
            tmp[0]=f2bf(f0.x); tmp[1]=f2bf(f0.y); tmp[2]=f2bf(f0.z); tmp[3]=f2bf(f0.w);
            tmp[4]=f2bf(f1.x); tmp[5]=f2bf(f1.y); tmp[6]=f2bf(f1.z); tmp[7]=f2bf(f1.w);
        } else {
            const unsigned short* src = (const unsigned short*)Aptr + (size_t)(m0 + r) * K + k0 + c0;
            *(uint4*)tmp = *(const uint4*)src;
        }
        *(uint4*)&As[r * 40 + c0] = *(const uint4*)tmp;
        *(uint4*)&Bs[r * 40 + c0] = *(const uint4*)(Bt + (size_t)(bn0 + r) * K + k0 + c0);
        __syncthreads();

        bf16x8 av = *(const bf16x8*)&As[(16 * w + ml) * 40 + kq];
#pragma unroll
        for (int ns = 0; ns < 4; ++ns) {
            bf16x8 bv = *(const bf16x8*)&Bs[(ns * 16 + ml) * 40 + kq];
            acc[ns] = __builtin_amdgcn_mfma_f32_16x16x32_bf16(av, bv, acc[ns], 0, 0, 0);
        }
        __syncthreads();
    }

#pragma unroll
    for (int ns = 0; ns < 4; ++ns) {
        int gn = bn0 + ns * 16 + ml;
        float bv = bias[gn];
#pragma unroll
        for (int rr = 0; rr < 4; ++rr) {
            int gm = m0 + 16 * w + q * 4 + rr;
            C[(size_t)gm * N + gn] = acc[ns][rr] + bv;
        }
    }
}

// ---------- MFMA scan: h_t = tanh(xw_t + h_{t-1} @ U), one WG (256 thr) per batch row ----------
// Double-buffered h in LDS, ONE lds-only barrier per step, 4-deep xw register pipeline.
// Steady-state loop has NO conditionals, pointer-bumped addressing, fast rcp,
// and twin accumulators (MFMA chain depth 4 instead of 8).
template<bool SEQ>
__global__ __launch_bounds__(256, 1) void rnn_scan_mfma(
    const float* __restrict__ xw,           // [64][512][256] f32
    const unsigned short* __restrict__ Ut,  // [256][256] bf16, Ut[n][k] = U[k][n]
    unsigned short* __restrict__ out_seq,   // bf16 [64][512][256]  (SEQ)
    float* __restrict__ out_last)           // f32 [64][256]        (!SEQ)
{
    const int b   = blockIdx.x;
    const int tid = threadIdx.x;
    const int w   = tid >> 6;       // wave 0..3
    const int L   = tid & 63;
    const int col = w * 64 + L;     // this thread's output column
    const int q   = L >> 4;         // quad
    const int ml  = L & 15;

    __shared__ unsigned short hsh[2][256];

    // B-fragments: U columns for this wave's 4 n-tiles, all 8 k-tiles
    bf16x8 ufrag[4][8];
#pragma unroll
    for (int i = 0; i < 4; ++i) {
        const unsigned short* up = Ut + (size_t)((w * 4 + i) * 16 + ml) * 256 + q * 8;
#pragma unroll
        for (int kt = 0; kt < 8; ++kt)
            ufrag[i][kt] = *(const bf16x8*)(up + kt * 32);
    }

    hsh[0][tid] = 0;   // bf16 +0.0

    const float* xb = xw + (size_t)b * 512 * 256 + col;
    unsigned short* op = SEQ ? out_seq + (size_t)b * 512 * 256 + col : nullptr;

    // 4-deep xw prefetch pipeline
    float xq0 = xb[0 * 256];
    float xq1 = xb[1 * 256];
    float xq2 = xb[2 * 256];
    float xq3 = xb[3 * 256];
    const float* xpf = xb + 4 * 256;

    float lastv = 0.f;
    __syncthreads();

#define SCAN_STEP(CUR, XQ, PF)                                                       \
    {                                                                                \
        bf16x8 af[8];                                                                \
        _Pragma("unroll")                                                            \
        for (int kt = 0; kt < 8; ++kt)                                               \
            af[kt] = *(const bf16x8*)&hsh[CUR][kt * 32 + q * 8];                     \
        float xnew = 0.f;                                                            \
        if (PF) { xnew = *xpf; xpf += 256; }                                         \
        f32x4 accA[4] = {}, accB[4] = {};                                            \
        _Pragma("unroll")                                                            \
        for (int kt = 0; kt < 8; kt += 2) {                                          \
            _Pragma("unroll")                                                        \
            for (int i = 0; i < 4; ++i)                                              \
                accA[i] = __builtin_amdgcn_mfma_f32_16x16x32_bf16(af[kt], ufrag[i][kt], accA[i], 0, 0, 0);       \
            _Pragma("unroll")                                                        \
            for (int i = 0; i < 4; ++i)                                              \
                accB[i] = __builtin_amdgcn_mfma_f32_16x16x32_bf16(af[kt + 1], ufrag[i][kt + 1], accB[i], 0, 0, 0); \
        }                                                                            \
        float zA = (q == 0) ? accA[0][0] : (q == 1) ? accA[1][0] : (q == 2) ? accA[2][0] : accA[3][0]; \
        float zB = (q == 0) ? accB[0][0] : (q == 1) ? accB[1][0] : (q == 2) ? accB[2][0] : accB[3][0]; \
        float z  = zA + zB + XQ;                                                     \
        float e  = __expf(2.f * z);               /* tanh(z) = 1 - 2/(e^{2z}+1) */   \
        float hn = 1.f - 2.f * __builtin_amdgcn_rcpf(e + 1.f);                       \
        lastv = hn;                                                                  \
        unsigned short hb = f2bf(hn);                                                \
        hsh[(CUR) ^ 1][col] = hb;                                                    \
        if (SEQ) { *op = hb; op += 256; }                                            \
        XQ = xnew;                                                                   \
        barrier_lds_only();                                                         \
    }

    // 127 chunks x 4 steps: t = 0..507, all prefetches in-bounds (last loads t=511)
    for (int tt = 0; tt < 508; tt += 4) {
        SCAN_STEP(0, xq0, 1)
        SCAN_STEP(1, xq1, 1)
        SCAN_STEP(0, xq2, 1)
        SCAN_STEP(1, xq3, 1)
    }
    // epilogue: t = 508..511, no prefetch
    SCAN_STEP(0, xq0, 0)
    SCAN_STEP(1, xq1, 0)
    SCAN_STEP(0, xq2, 0)
    SCAN_STEP(1, xq3, 0)
#undef SCAN_STEP

    if (!SEQ) out_last[b * 256 + col] = lastv;
}

// ---------- head: softmax(h2 @ Wd + bd) ----------
__global__ void head_kernel(const float* __restrict__ h2, const float* __restrict__ Wd,
                            const float* __restrict__ bd, float* __restrict__ out)
{
    int tid = threadIdx.x;         // 128 threads: b = tid>>1, c = tid&1
    int b = tid >> 1, c = tid & 1;
    float s = bd[c];
    for (int jj = 0; jj < 256; ++jj) s = fmaf(h2[b * 256 + jj], Wd[jj * 2 + c], s);
    __shared__ float lg[128];
    lg[tid] = s;
    __syncthreads();
    float o0 = lg[b * 2 + 0], o1 = lg[b * 2 + 1];
    float m = fmaxf(o0, o1);
    float z = __expf(o0 - m) + __expf(o1 - m);
    out[tid] = __expf(s - m) * __builtin_amdgcn_rcpf(z);
}

// ---------- launch ----------
extern "C" void kernel_launch(void* const* d_in, const int* in_sizes, int n_in,
                              void* d_out, int out_size, void* d_ws, size_t ws_size,
                              hipStream_t stream) {
    const int*   tokens = (const int*)d_in[0];
    const float* emb    = (const float*)d_in[1];
    const float* W1     = (const float*)d_in[2];
    const float* U1     = (const float*)d_in[3];
    const float* b1     = (const float*)d_in[4];
    const float* W2     = (const float*)d_in[5];
    const float* U2     = (const float*)d_in[6];
    const float* b2     = (const float*)d_in[7];
    const float* Wd     = (const float*)d_in[8];
    const float* bd     = (const float*)d_in[9];
    float* out = (float*)d_out;

    char* ws = (char*)d_ws;
    float*          xw  = (float*)ws;                                  // 32 MB (xw1 then xw2)
    unsigned short* h1  = (unsigned short*)(ws + (33554432));          // 16 MB bf16
    char*           p   = ws + 33554432 + 16777216;
    unsigned short* W1t = (unsigned short*)p;            p += 512 * 256 * 2;
    unsigned short* W2t = (unsigned short*)p;            p += 256 * 256 * 2;
    unsigned short* U1t = (unsigned short*)p;            p += 256 * 256 * 2;
    unsigned short* U2t = (unsigned short*)p;            p += 256 * 256 * 2;
    float*          h2  = (float*)p;

    const int M = 64 * 512;   // 32768

    // K0: weight/recurrence transposes to bf16 [N][K]
    transpose4<<<dim3(512, 4), 256, 0, stream>>>(W1, W2, U1, U2, W1t, W2t, U1t, U2t);

    // K1: xw1 = emb[tokens] @ W1 + b1   (gather fused)
    gemm_mfma<true><<<dim3(256 / 64, M / 64), 256, 0, stream>>>(
        emb, tokens, W1t, b1, xw, M, 256, 512);

    // K2: layer-1 scan -> h1 (bf16 sequence)
    rnn_scan_mfma<true><<<64, 256, 0, stream>>>(xw, U1t, h1, nullptr);

    // K3: xw2 = h1 @ W2 + b2
    gemm_mfma<false><<<dim3(256 / 64, M / 64), 256, 0, stream>>>(
        h1, nullptr, W2t, b2, xw, M, 256, 256);

    // K4: layer-2 scan -> h2 (last state, f32)
    rnn_scan_mfma<false><<<64, 256, 0, stream>>>(xw, U2t, nullptr, h2);

    // K5: softmax(h2 @ Wd + bd)
    head_kernel<<<1, 128, 0, stream>>>(h2, Wd, bd, out);
}